// Round 4
// baseline (3663.235 us; speedup 1.0000x reference)
//
#include <hip/hip_runtime.h>

typedef _Float16 half8 __attribute__((ext_vector_type(8)));
typedef float float4v __attribute__((ext_vector_type(4)));
typedef unsigned long long u64;

#define TSEQ  1024
#define BATCH 128
#define HID   512
#define DIN   128

// LDS: double-buffered h tile. Row stride 264 b32-words (528 halves) so the
// MFMA ds_read_b128 pattern lands 2-way max (free).
#define HW_STRIDE 264                        // b32 words per row
#define HBUF_WORDS (8 * HW_STRIDE)           // 2112 words per buffer
#define GOFF (2 * HBUF_WORDS * 4)            // 16896 B
#define LDS_BYTES (GOFF + 4 * 8 * 32 * 4)    // + per-wave gate scratch = 20992 B

// d_ws layout
#define WS_H16_OFF  0                                // [2][128][512] fp16 = 256 KiB
#define WS_BAR_OFF  (2 * BATCH * HID * 2)            // 262144: bar[0]=barrier, bar[1..256]=xcc ids
#define WS_XALL_OFF (1u << 20)                       // 1 MiB
#define WS_NEED     ((size_t)WS_XALL_OFF + (size_t)TSEQ * BATCH * DIN * 2)

__device__ inline half8 cvt8(float4v a, float4v b) {
    half8 r;
    r[0] = (_Float16)a[0]; r[1] = (_Float16)a[1];
    r[2] = (_Float16)a[2]; r[3] = (_Float16)a[3];
    r[4] = (_Float16)b[0]; r[5] = (_Float16)b[1];
    r[6] = (_Float16)b[2]; r[7] = (_Float16)b[3];
    return r;
}

// branch-free sigmoid / tanh on v_exp_f32 + v_rcp_f32
__device__ inline float sigm(float x) {
    return __builtin_amdgcn_rcpf(1.0f + __builtin_amdgcn_exp2f(-1.44269504f * x));
}
__device__ inline float tanh_fast(float x) { return 2.0f * sigm(2.0f * x) - 1.0f; }

__device__ inline int get_xcc_id() {
    int x;
    asm volatile("s_getreg_b32 %0, hwreg(HW_REG_XCC_ID)" : "=s"(x));
    return x;
}

// sc0 (XCD-scope) single-word load: bypasses per-CU L1, served by the shared
// per-XCD L2 — used for cheap RETRIES only (round 0 stays agent-scope).
// R1 lesson: sc0 loads alone starve when the producer STORE is scope-0 (CU);
// this round pairs them with an sc0 producer store (write-through to L2).
__device__ inline u64 ld1_sc0(const u64* p) {
    u64 v;
    asm volatile("global_load_dwordx2 %0, %1, off sc0\n\t"
                 "s_waitcnt vmcnt(0)"
                 : "=&v"(v) : "v"(p) : "memory");
    return v;
}

// 16 teams x 16 CUs. Team owns rows [8t,8t+8); CU p owns units [32p,32p+32);
// wave w owns units [..+8w..). Weights VGPR-resident fp16 for the whole run.
// h handoff: RAW fp16, double-buffered, mantissa LSB = phase ((t>>1)&1)^1 —
// each 2-byte value self-describes freshness; relaxed atomics suffice.
// Publish = (fast only) sc0 store (XCD-L2 write-through) + agent store
// (IF visibility — the guaranteed backstop; same bytes, same addr).
// Poll = agent round 0 (baseline, never regresses) + sc0 retries (~300cyc L2
// RT vs ~850cyc IF RT); every 3rd retry is agent-scope for guaranteed
// progress even if sc0 never coheres. fast requires XCC-uniform team
// (runtime-checked via HW_REG_XCC_ID through the one-time grid barrier).
// Poison 0xAAAA has LSB 0 != first expected phase 1 -> no init required.
// Step: poll(h(t-1)) -> barrier -> h-MFMAs (8 chains) -> gates ->
// publish h(t) -> [filler: x rotate/prefetch + x-MFMA(t+1)] -> s_sleep(6).
template <bool XA>
__global__ __launch_bounds__(256, 1)
void lstm_persistent(const int* __restrict__ ids,
                     const int* __restrict__ seq_len,
                     const float* __restrict__ emb,
                     const float* __restrict__ w_ih,
                     const float* __restrict__ w_hh,
                     const float* __restrict__ b_ih,
                     const float* __restrict__ b_hh,
                     float* __restrict__ out,
                     _Float16* __restrict__ h16,      // [2][128][512] fp16
                     _Float16* __restrict__ x_all,    // [T][128][128] fp16
                     int* __restrict__ bar)
{
    __shared__ __align__(16) char smem[LDS_BYTES];
    __shared__ int fastflag;
    unsigned* hsu = (unsigned*)smem;
    _Float16* hsh = (_Float16*)smem;
    float*    gs  = (float*)(smem + GOFF);

    const int tid  = threadIdx.x;
    const int lane = tid & 63;
    const int wv   = tid >> 6;
    const int team = blockIdx.x & 15;
    const int p    = blockIdx.x >> 4;
    const int rowbase   = team * 8;
    const int unit_base = p * 32 + wv * 8;

    const int col  = lane & 15;   // MFMA n / C col
    const int kq   = lane >> 4;   // MFMA k-quad
    const int arow = lane & 7;    // A row (rows 8..15 duplicate 0..7)
    const int my_row  = lane >> 3;
    const int my_unit = unit_base + (lane & 7);

    if (XA) {
        // ---- phase 0: gather x_all[t][b][:] = fp16(emb[ids[t][b]][:]) ----
        for (int pair = blockIdx.x * 256 + tid; pair < TSEQ * BATCH;
             pair += 256 * 256) {
            const float* src = emb + (size_t)ids[pair] * DIN;   // pair = t*128+b
            _Float16* dst = x_all + (size_t)pair * DIN;
#pragma unroll
            for (int k = 0; k < 16; ++k) {
                float4v a = *(const float4v*)(src + k * 8);
                float4v c = *(const float4v*)(src + k * 8 + 4);
                *(half8*)(dst + k * 8) = cvt8(a, c);
            }
        }
        // publish this block's XCD id before the barrier's release
        if (tid == 0) bar[1 + blockIdx.x] = get_xcc_id() + 1;
        // ---- one-time grid barrier (full release/acquire, only here) ----
        __threadfence();
        __syncthreads();
        if (tid == 0) {
            __hip_atomic_fetch_add(bar, 1, __ATOMIC_RELEASE,
                                   __HIP_MEMORY_SCOPE_AGENT);
            int g = 0;
            while (__hip_atomic_load(bar, __ATOMIC_ACQUIRE,
                                     __HIP_MEMORY_SCOPE_AGENT) < 256
                   && ++g < (1 << 26)) { }
        }
        __syncthreads();
        __threadfence();
        // ---- team XCD-uniformity check (enables sc0 fast paths) ----
        if (tid == 0) {
            const int mine = get_xcc_id() + 1;
            int f = 1;
            for (int pp = 0; pp < 16; ++pp) {
                int xv = __hip_atomic_load(bar + 1 + (16 * pp + team),
                                           __ATOMIC_RELAXED,
                                           __HIP_MEMORY_SCOPE_AGENT);
                f &= (xv == mine);
            }
            fastflag = f;
        }
        __syncthreads();
    }
    const int fast = XA ? fastflag : 0;

    int tmax = 0, my_tstar = 0;
    for (int r = 0; r < 8; ++r) {
        int s  = seq_len[rowbase + r];
        int ts = (s > 0) ? (s - 1) : 0;
        if (r == my_row) my_tstar = ts;
        tmax = (ts > tmax) ? ts : tmax;
    }

    // ---- weight fragments -> VGPRs (fp32 -> fp16), once ----
    const int wrow0 = (col & 3) * HID + unit_base + (col >> 2);
    const int wrow1 = (col & 3) * HID + unit_base + 4 + (col >> 2);
    const float bias0 = b_ih[wrow0] + b_hh[wrow0];
    const float bias1 = b_ih[wrow1] + b_hh[wrow1];

    half8 whhf0[16], whhf1[16];
#pragma unroll
    for (int kt = 0; kt < 16; ++kt) {
        const float* s0 = w_hh + (size_t)wrow0 * HID + kt * 32 + kq * 8;
        const float* s1 = w_hh + (size_t)wrow1 * HID + kt * 32 + kq * 8;
        whhf0[kt] = cvt8(*(const float4v*)s0, *(const float4v*)(s0 + 4));
        whhf1[kt] = cvt8(*(const float4v*)s1, *(const float4v*)(s1 + 4));
    }
    half8 wihf0[4], wihf1[4];
#pragma unroll
    for (int kt = 0; kt < 4; ++kt) {
        const float* s0 = w_ih + (size_t)wrow0 * DIN + kt * 32 + kq * 8;
        const float* s1 = w_ih + (size_t)wrow1 * DIN + kt * 32 + kq * 8;
        wihf0[kt] = cvt8(*(const float4v*)s0, *(const float4v*)(s0 + 4));
        wihf1[kt] = cvt8(*(const float4v*)s1, *(const float4v*)(s1 + 4));
    }

    float c_state = 0.0f;
    const int crow = tid >> 5;    // poll/staging: row 0..7, 32 threads/row
    const int coff = tid & 31;    // thread polls u64s {coff + 32j}, j=0..3

    // ---- x fragment pipeline ----
    half8 xf[4], xn[4];
    if (XA) {
        const _Float16* x0 = x_all + ((size_t)0 * BATCH + rowbase + arow) * DIN;
        const int t1 = (tmax > 0) ? 1 : 0;
        const _Float16* x1 = x_all + ((size_t)t1 * BATCH + rowbase + arow) * DIN;
#pragma unroll
        for (int kt = 0; kt < 4; ++kt) {
            xf[kt] = *(const half8*)(x0 + kt * 32 + kq * 8);
            xn[kt] = *(const half8*)(x1 + kt * 32 + kq * 8);
        }
    } else {
        const int id0 = ids[rowbase + arow];
        const float* xrow = emb + (size_t)id0 * DIN;
#pragma unroll
        for (int kt = 0; kt < 4; ++kt) {
            const float* s = xrow + kt * 32 + kq * 8;
            xf[kt] = cvt8(*(const float4v*)s, *(const float4v*)(s + 4));
        }
    }

    // ---- acc(0) = bias + x(0) @ Wih, spread over 8 chains (a..d x 2) ----
    float4v a0 = {bias0, bias0, bias0, bias0}, b0 = {0,0,0,0}, c0 = {0,0,0,0}, d0 = {0,0,0,0};
    float4v a1 = {bias1, bias1, bias1, bias1}, b1 = {0,0,0,0}, c1 = {0,0,0,0}, d1 = {0,0,0,0};
    a0 = __builtin_amdgcn_mfma_f32_16x16x32_f16(xf[0], wihf0[0], a0, 0, 0, 0);
    b0 = __builtin_amdgcn_mfma_f32_16x16x32_f16(xf[1], wihf0[1], b0, 0, 0, 0);
    c0 = __builtin_amdgcn_mfma_f32_16x16x32_f16(xf[2], wihf0[2], c0, 0, 0, 0);
    d0 = __builtin_amdgcn_mfma_f32_16x16x32_f16(xf[3], wihf0[3], d0, 0, 0, 0);
    a1 = __builtin_amdgcn_mfma_f32_16x16x32_f16(xf[0], wihf1[0], a1, 0, 0, 0);
    b1 = __builtin_amdgcn_mfma_f32_16x16x32_f16(xf[1], wihf1[1], b1, 0, 0, 0);
    c1 = __builtin_amdgcn_mfma_f32_16x16x32_f16(xf[2], wihf1[2], c1, 0, 0, 0);
    d1 = __builtin_amdgcn_mfma_f32_16x16x32_f16(xf[3], wihf1[3], d1, 0, 0, 0);

    const u64 LSBM = 0x0001000100010001ull;

    for (int t = 0; t <= tmax; ++t) {
        const int bs = t & 1;    // LDS h-tile buffer for this step
        int id_next = 0;
        if (!XA) {
            const int tn = (t < tmax) ? (t + 1) : t;
            id_next = ids[tn * BATCH + rowbase + arow];
        }

        if (t > 0) {
            // ---- poll teammates' phase-tagged fp16 h (poll IS the load) ----
            const u64* rowp = (const u64*)(h16
                + (size_t)((t + 1) & 1) * BATCH * HID + (rowbase + crow) * HID);
            const u64 want = ((((t - 1) >> 1) & 1) ^ 1) ? LSBM : 0ull;
            unsigned* dstw = hsu + bs * HBUF_WORDS + crow * HW_STRIDE + 2 * coff;
            u64 v[4];
            unsigned pending = 0xF;
#pragma unroll
            for (int j = 0; j < 4; ++j)
                v[j] = __hip_atomic_load(rowp + coff + 32 * j,
                                         __ATOMIC_RELAXED, __HIP_MEMORY_SCOPE_AGENT);
#pragma unroll
            for (int j = 0; j < 4; ++j) {
                if (((v[j] ^ want) & LSBM) == 0) {
                    *(u64*)(dstw + 64 * j) = v[j];
                    pending &= ~(1u << j);
                }
            }
            int round = 0, guard = 0;
            while (pending) {
#pragma unroll
                for (int j = 0; j < 4; ++j) {
                    if (pending & (1u << j)) {
                        // fast: cheap XCD-L2 retries; every 3rd round agent
                        // (guaranteed progress if sc0 never coheres)
                        u64 x = (fast && (round % 3) != 2)
                                  ? ld1_sc0(rowp + coff + 32 * j)
                                  : __hip_atomic_load(rowp + coff + 32 * j,
                                                      __ATOMIC_RELAXED,
                                                      __HIP_MEMORY_SCOPE_AGENT);
                        if (((x ^ want) & LSBM) == 0) {
                            *(u64*)(dstw + 64 * j) = x;
                            pending &= ~(1u << j);
                        }
                    }
                }
                if (!pending) break;
                ++round;
                if (!fast && round >= 3) __builtin_amdgcn_s_sleep(1);
                if (++guard > (1 << 20)) break;   // anti-hang safety valve
            }
        }
        __syncthreads();   // the ONLY barrier per step (h-tile double-buffered)

        float4v xraw[8];
        if (!XA) {
            // fallback: issue emb(t+1) raw loads here (h-MFMA shadow)
            const float* xrow = emb + (size_t)id_next * DIN;
#pragma unroll
            for (int kt = 0; kt < 4; ++kt) {
                xraw[2 * kt]     = *(const float4v*)(xrow + kt * 32 + kq * 8);
                xraw[2 * kt + 1] = *(const float4v*)(xrow + kt * 32 + kq * 8 + 4);
            }
        }

        if (t > 0) {
            // ---- h MFMAs: 16 kt over 8 chains (dependent depth 4) ----
            const _Float16* hb = hsh + bs * HBUF_WORDS * 2;
#pragma unroll
            for (int kt = 0; kt < 16; ++kt) {
                half8 af = *(const half8*)(hb + arow * (HW_STRIDE * 2) + kt * 32 + kq * 8);
                switch (kt & 3) {
                case 0:
                    a0 = __builtin_amdgcn_mfma_f32_16x16x32_f16(af, whhf0[kt], a0, 0, 0, 0);
                    a1 = __builtin_amdgcn_mfma_f32_16x16x32_f16(af, whhf1[kt], a1, 0, 0, 0);
                    break;
                case 1:
                    b0 = __builtin_amdgcn_mfma_f32_16x16x32_f16(af, whhf0[kt], b0, 0, 0, 0);
                    b1 = __builtin_amdgcn_mfma_f32_16x16x32_f16(af, whhf1[kt], b1, 0, 0, 0);
                    break;
                case 2:
                    c0 = __builtin_amdgcn_mfma_f32_16x16x32_f16(af, whhf0[kt], c0, 0, 0, 0);
                    c1 = __builtin_amdgcn_mfma_f32_16x16x32_f16(af, whhf1[kt], c1, 0, 0, 0);
                    break;
                default:
                    d0 = __builtin_amdgcn_mfma_f32_16x16x32_f16(af, whhf0[kt], d0, 0, 0, 0);
                    d1 = __builtin_amdgcn_mfma_f32_16x16x32_f16(af, whhf1[kt], d1, 0, 0, 0);
                }
            }
        }
        const float4v g0 = (a0 + b0) + (c0 + d0);
        const float4v g1 = (a1 + b1) + (c1 + d1);

        // ---- regroup i,f,g,o per (row,unit) via per-wave LDS scratch ----
        float* gw = gs + wv * 256;
        if (lane < 32) {
            const int grow = (lane >> 4) * 4;
#pragma unroll
            for (int r = 0; r < 4; ++r) {
                gw[(grow + r) * 32 + col]      = g0[r];
                gw[(grow + r) * 32 + 16 + col] = g1[r];
            }
        }
        const float4v g4 = *(const float4v*)(gw + my_row * 32 + (lane & 7) * 4);

        const float i_s = sigm(g4[0]);
        const float f_s = sigm(g4[1]);
        const float g_t = tanh_fast(g4[2]);
        const float o_s = sigm(g4[3]);
        c_state = f_s * c_state + i_s * g_t;
        const float hn = o_s * tanh_fast(c_state);

        if (t == my_tstar)
            out[(rowbase + my_row) * HID + my_unit] = c_state;

        // ---- publish h: raw fp16, mantissa LSB = phase; fire-and-forget ----
        {
            const unsigned pub_phase = (((unsigned)t >> 1) & 1u) ^ 1u;
            unsigned short hb16 = __builtin_bit_cast(unsigned short, (_Float16)hn);
            hb16 = (unsigned short)((hb16 & 0xFFFEu) | pub_phase);
            unsigned short* hdst = (unsigned short*)h16
                + (size_t)(t & 1) * BATCH * HID
                + (rowbase + my_row) * HID + my_unit;
            if (fast) {
                // XCD-L2 write-through publish (feeds teammates' sc0 retries)
                unsigned hv = hb16;
                asm volatile("global_store_short %0, %1, off sc0"
                             :: "v"(hdst), "v"(hv) : "memory");
            }
            // guaranteed IF visibility (baseline publish; agent backstop)
            __hip_atomic_store(hdst, hb16, __ATOMIC_RELAXED,
                               __HIP_MEMORY_SCOPE_AGENT);
        }

        // ---- filler between publish and next poll: x pipeline + x-MFMA(t+1)
        //      then a tuned s_sleep so poll round-0 samples the IF *after*
        //      producer visibility (converts 2-3 serial poll RTs into ~1) ----
        if (XA) {
#pragma unroll
            for (int kt = 0; kt < 4; ++kt) xf[kt] = xn[kt];
            const int t2 = (t + 2 <= tmax) ? (t + 2) : tmax;
            const _Float16* xs2 = x_all + ((size_t)t2 * BATCH + rowbase + arow) * DIN;
#pragma unroll
            for (int kt = 0; kt < 4; ++kt)
                xn[kt] = *(const half8*)(xs2 + kt * 32 + kq * 8);
        } else {
#pragma unroll
            for (int kt = 0; kt < 4; ++kt)
                xf[kt] = cvt8(xraw[2 * kt], xraw[2 * kt + 1]);
        }

        a0 = (float4v){bias0, bias0, bias0, bias0}; b0 = (float4v){0,0,0,0};
        c0 = (float4v){0,0,0,0};                    d0 = (float4v){0,0,0,0};
        a1 = (float4v){bias1, bias1, bias1, bias1}; b1 = (float4v){0,0,0,0};
        c1 = (float4v){0,0,0,0};                    d1 = (float4v){0,0,0,0};
        a0 = __builtin_amdgcn_mfma_f32_16x16x32_f16(xf[0], wihf0[0], a0, 0, 0, 0);
        b0 = __builtin_amdgcn_mfma_f32_16x16x32_f16(xf[1], wihf0[1], b0, 0, 0, 0);
        c0 = __builtin_amdgcn_mfma_f32_16x16x32_f16(xf[2], wihf0[2], c0, 0, 0, 0);
        d0 = __builtin_amdgcn_mfma_f32_16x16x32_f16(xf[3], wihf0[3], d0, 0, 0, 0);
        a1 = __builtin_amdgcn_mfma_f32_16x16x32_f16(xf[0], wihf1[0], a1, 0, 0, 0);
        b1 = __builtin_amdgcn_mfma_f32_16x16x32_f16(xf[1], wihf1[1], b1, 0, 0, 0);
        c1 = __builtin_amdgcn_mfma_f32_16x16x32_f16(xf[2], wihf1[2], c1, 0, 0, 0);
        d1 = __builtin_amdgcn_mfma_f32_16x16x32_f16(xf[3], wihf1[3], d1, 0, 0, 0);

        // tuned pre-poll delay: ~384 cyc (producer store->IF visibility + skew)
        __builtin_amdgcn_s_sleep(6);
    }
}

extern "C" void kernel_launch(void* const* d_in, const int* in_sizes, int n_in,
                              void* d_out, int out_size, void* d_ws, size_t ws_size,
                              hipStream_t stream)
{
    const int*   ids  = (const int*)d_in[0];
    const int*   slen = (const int*)d_in[1];
    const float* emb  = (const float*)d_in[2];
    const float* wih  = (const float*)d_in[3];
    const float* whh  = (const float*)d_in[4];
    const float* bih  = (const float*)d_in[5];
    const float* bhh  = (const float*)d_in[6];
    float* out = (float*)d_out;

    _Float16* h16   = (_Float16*)((char*)d_ws + WS_H16_OFF);
    int*      bar   = (int*)((char*)d_ws + WS_BAR_OFF);
    _Float16* x_all = (_Float16*)((char*)d_ws + WS_XALL_OFF);

    if (ws_size >= WS_NEED) {
        hipMemsetAsync(bar, 0, sizeof(int), stream);
        hipLaunchKernelGGL((lstm_persistent<true>), dim3(256), dim3(256), 0, stream,
                           ids, slen, emb, wih, whh, bih, bhh, out,
                           h16, x_all, bar);
    } else {
        hipLaunchKernelGGL((lstm_persistent<false>), dim3(256), dim3(256), 0, stream,
                           ids, slen, emb, wih, whh, bih, bhh, out,
                           h16, x_all, bar);
    }
}

// Round 5
// 3533.513 us; speedup vs baseline: 1.0367x; 1.0367x over previous
//
#include <hip/hip_runtime.h>

typedef _Float16 half8 __attribute__((ext_vector_type(8)));
typedef float float4v __attribute__((ext_vector_type(4)));
typedef unsigned long long u64;

#define TSEQ  1024
#define BATCH 128
#define HID   512
#define DIN   128

// LDS: 4 h tiles (2 teams x double-buffer). Row stride 264 b32-words so the
// MFMA ds_read_b128 pattern lands 2-way max (free).
#define HW_STRIDE 264                        // b32 words per row
#define HBUF_WORDS (8 * HW_STRIDE)           // 2112 words per tile
#define GOFF (4 * HBUF_WORDS * 4)            // 33792 B (tiles A0,A1,B0,B1)
#define LDS_BYTES (GOFF + 4 * 8 * 32 * 4)    // + per-wave gate scratch = 37888 B

// d_ws layout
#define WS_H16_OFF  0                                // [2][128][512] fp16 = 256 KiB
#define WS_BAR_OFF  (2 * BATCH * HID * 2)            // 262144
#define WS_XALL_OFF (1u << 20)                       // 1 MiB
#define WS_NEED     ((size_t)WS_XALL_OFF + (size_t)TSEQ * BATCH * DIN * 2)

__device__ inline half8 cvt8(float4v a, float4v b) {
    half8 r;
    r[0] = (_Float16)a[0]; r[1] = (_Float16)a[1];
    r[2] = (_Float16)a[2]; r[3] = (_Float16)a[3];
    r[4] = (_Float16)b[0]; r[5] = (_Float16)b[1];
    r[6] = (_Float16)b[2]; r[7] = (_Float16)b[3];
    return r;
}

// branch-free sigmoid / tanh on v_exp_f32 + v_rcp_f32
__device__ inline float sigm(float x) {
    return __builtin_amdgcn_rcpf(1.0f + __builtin_amdgcn_exp2f(-1.44269504f * x));
}
__device__ inline float tanh_fast(float x) { return 2.0f * sigm(2.0f * x) - 1.0f; }

// DUAL-TEAM persistent LSTM. 128 blocks: block b serves unit-slice
// p = b>>3 (units [32p,32p+32)) for BOTH teams of pair k = b&7
// (teamA rows [16k,16k+8), teamB rows [16k+8,16k+16) — adjacent, so sorted
// seq_len keeps both alive ~equally long). W_ih/W_hh columns depend only on
// the unit index -> the VGPR-resident weight set is SHARED by both teams;
// only acc/x-pipe/c_state duplicate (~70 VGPRs).
// h handoff (per team, UNCHANGED from the proven R3 protocol): RAW fp16,
// double-buffered, mantissa LSB = phase ((t>>1)&1)^1; relaxed AGENT atomics.
// [R1/R2/R4 lesson: every sc0/L2-local variant starves or regresses on
//  gfx950 — do not touch the exchange scope.]
// Poison 0xAAAA has LSB 0 != first expected phase 1 -> no init required.
// Step schedule (the point of this round): two STAGGERED phases per iter —
//   pollA -> bar -> hMFMA A -> gates A -> publish A -> x-filler A ->
//   pollB -> bar -> hMFMA B -> gates B -> publish B -> x-filler B
// The publish->poll gap for each team is now a full opposite-team phase
// (~1500 cyc of useful work) instead of a tuned sleep, so poll round-0
// samples the IF after producer visibility and the step pays ~one RT.
// All 16 blocks of a pair iterate to the same tmax -> no starvation.
template <bool XA>
__global__ __launch_bounds__(256, 1)
void lstm_persistent(const int* __restrict__ ids,
                     const int* __restrict__ seq_len,
                     const float* __restrict__ emb,
                     const float* __restrict__ w_ih,
                     const float* __restrict__ w_hh,
                     const float* __restrict__ b_ih,
                     const float* __restrict__ b_hh,
                     float* __restrict__ out,
                     _Float16* __restrict__ h16,      // [2][128][512] fp16
                     _Float16* __restrict__ x_all,    // [T][128][128] fp16
                     int* __restrict__ bar)
{
    __shared__ __align__(16) char smem[LDS_BYTES];
    unsigned* hsu = (unsigned*)smem;
    _Float16* hsh = (_Float16*)smem;
    float*    gs  = (float*)(smem + GOFF);

    const int tid  = threadIdx.x;
    const int lane = tid & 63;
    const int wv   = tid >> 6;
    const int pairk = blockIdx.x & 7;
    const int p     = blockIdx.x >> 3;
    const int rowbaseA = pairk * 16;
    const int rowbaseB = pairk * 16 + 8;
    const int unit_base = p * 32 + wv * 8;

    const int col  = lane & 15;   // MFMA n / C col
    const int kq   = lane >> 4;   // MFMA k-quad
    const int arow = lane & 7;    // A row (rows 8..15 duplicate 0..7)
    const int my_row  = lane >> 3;
    const int my_unit = unit_base + (lane & 7);

    if (XA) {
        // ---- phase 0: gather x_all[t][b][:] = fp16(emb[ids[t][b]][:]) ----
        for (int pr = blockIdx.x * 256 + tid; pr < TSEQ * BATCH;
             pr += 128 * 256) {
            const float* src = emb + (size_t)ids[pr] * DIN;   // pr = t*128+b
            _Float16* dst = x_all + (size_t)pr * DIN;
#pragma unroll
            for (int k = 0; k < 16; ++k) {
                float4v a = *(const float4v*)(src + k * 8);
                float4v c = *(const float4v*)(src + k * 8 + 4);
                *(half8*)(dst + k * 8) = cvt8(a, c);
            }
        }
        // ---- one-time grid barrier (full release/acquire, only here) ----
        __threadfence();
        __syncthreads();
        if (tid == 0) {
            __hip_atomic_fetch_add(bar, 1, __ATOMIC_RELEASE,
                                   __HIP_MEMORY_SCOPE_AGENT);
            int g = 0;
            while (__hip_atomic_load(bar, __ATOMIC_ACQUIRE,
                                     __HIP_MEMORY_SCOPE_AGENT) < (int)gridDim.x
                   && ++g < (1 << 26)) { }
        }
        __syncthreads();
        __threadfence();
    }

    int tmax = 0, my_tstarA = 0, my_tstarB = 0;
    for (int r = 0; r < 16; ++r) {
        int s  = seq_len[pairk * 16 + r];
        int ts = (s > 0) ? (s - 1) : 0;
        if (r == my_row)     my_tstarA = ts;
        if (r == 8 + my_row) my_tstarB = ts;
        tmax = (ts > tmax) ? ts : tmax;
    }

    // ---- weight fragments -> VGPRs (fp32 -> fp16), once; SHARED by teams ----
    const int wrow0 = (col & 3) * HID + unit_base + (col >> 2);
    const int wrow1 = (col & 3) * HID + unit_base + 4 + (col >> 2);
    const float bias0 = b_ih[wrow0] + b_hh[wrow0];
    const float bias1 = b_ih[wrow1] + b_hh[wrow1];

    half8 whhf0[16], whhf1[16];
#pragma unroll
    for (int kt = 0; kt < 16; ++kt) {
        const float* s0 = w_hh + (size_t)wrow0 * HID + kt * 32 + kq * 8;
        const float* s1 = w_hh + (size_t)wrow1 * HID + kt * 32 + kq * 8;
        whhf0[kt] = cvt8(*(const float4v*)s0, *(const float4v*)(s0 + 4));
        whhf1[kt] = cvt8(*(const float4v*)s1, *(const float4v*)(s1 + 4));
    }
    half8 wihf0[4], wihf1[4];
#pragma unroll
    for (int kt = 0; kt < 4; ++kt) {
        const float* s0 = w_ih + (size_t)wrow0 * DIN + kt * 32 + kq * 8;
        const float* s1 = w_ih + (size_t)wrow1 * DIN + kt * 32 + kq * 8;
        wihf0[kt] = cvt8(*(const float4v*)s0, *(const float4v*)(s0 + 4));
        wihf1[kt] = cvt8(*(const float4v*)s1, *(const float4v*)(s1 + 4));
    }

    float cA = 0.0f, cB = 0.0f;
    const int crow = tid >> 5;    // poll/staging: row 0..7, 32 threads/row
    const int coff = tid & 31;    // thread polls u64s {coff + 32j}, j=0..3

    // ---- x fragment pipelines (per team) ----
    half8 xfA[4], xnA[4], xfB[4], xnB[4];
    if (XA) {
        const int t1 = (tmax > 0) ? 1 : 0;
        const _Float16* a0p = x_all + ((size_t)0 * BATCH + rowbaseA + arow) * DIN;
        const _Float16* a1p = x_all + ((size_t)t1 * BATCH + rowbaseA + arow) * DIN;
        const _Float16* b0p = x_all + ((size_t)0 * BATCH + rowbaseB + arow) * DIN;
        const _Float16* b1p = x_all + ((size_t)t1 * BATCH + rowbaseB + arow) * DIN;
#pragma unroll
        for (int kt = 0; kt < 4; ++kt) {
            xfA[kt] = *(const half8*)(a0p + kt * 32 + kq * 8);
            xnA[kt] = *(const half8*)(a1p + kt * 32 + kq * 8);
            xfB[kt] = *(const half8*)(b0p + kt * 32 + kq * 8);
            xnB[kt] = *(const half8*)(b1p + kt * 32 + kq * 8);
        }
    } else {
        const int idA = ids[rowbaseA + arow];
        const int idB = ids[rowbaseB + arow];
        const float* xa = emb + (size_t)idA * DIN;
        const float* xb = emb + (size_t)idB * DIN;
#pragma unroll
        for (int kt = 0; kt < 4; ++kt) {
            const float* sa = xa + kt * 32 + kq * 8;
            const float* sb = xb + kt * 32 + kq * 8;
            xfA[kt] = cvt8(*(const float4v*)sa, *(const float4v*)(sa + 4));
            xfB[kt] = cvt8(*(const float4v*)sb, *(const float4v*)(sb + 4));
        }
    }

    // ---- acc(0) = bias + x(0) @ Wih, 8 chains per team ----
    float4v Aa0 = {bias0, bias0, bias0, bias0}, Ab0 = {0,0,0,0}, Ac0 = {0,0,0,0}, Ad0 = {0,0,0,0};
    float4v Aa1 = {bias1, bias1, bias1, bias1}, Ab1 = {0,0,0,0}, Ac1 = {0,0,0,0}, Ad1 = {0,0,0,0};
    float4v Ba0 = {bias0, bias0, bias0, bias0}, Bb0 = {0,0,0,0}, Bc0 = {0,0,0,0}, Bd0 = {0,0,0,0};
    float4v Ba1 = {bias1, bias1, bias1, bias1}, Bb1 = {0,0,0,0}, Bc1 = {0,0,0,0}, Bd1 = {0,0,0,0};
    Aa0 = __builtin_amdgcn_mfma_f32_16x16x32_f16(xfA[0], wihf0[0], Aa0, 0, 0, 0);
    Ab0 = __builtin_amdgcn_mfma_f32_16x16x32_f16(xfA[1], wihf0[1], Ab0, 0, 0, 0);
    Ac0 = __builtin_amdgcn_mfma_f32_16x16x32_f16(xfA[2], wihf0[2], Ac0, 0, 0, 0);
    Ad0 = __builtin_amdgcn_mfma_f32_16x16x32_f16(xfA[3], wihf0[3], Ad0, 0, 0, 0);
    Aa1 = __builtin_amdgcn_mfma_f32_16x16x32_f16(xfA[0], wihf1[0], Aa1, 0, 0, 0);
    Ab1 = __builtin_amdgcn_mfma_f32_16x16x32_f16(xfA[1], wihf1[1], Ab1, 0, 0, 0);
    Ac1 = __builtin_amdgcn_mfma_f32_16x16x32_f16(xfA[2], wihf1[2], Ac1, 0, 0, 0);
    Ad1 = __builtin_amdgcn_mfma_f32_16x16x32_f16(xfA[3], wihf1[3], Ad1, 0, 0, 0);
    Ba0 = __builtin_amdgcn_mfma_f32_16x16x32_f16(xfB[0], wihf0[0], Ba0, 0, 0, 0);
    Bb0 = __builtin_amdgcn_mfma_f32_16x16x32_f16(xfB[1], wihf0[1], Bb0, 0, 0, 0);
    Bc0 = __builtin_amdgcn_mfma_f32_16x16x32_f16(xfB[2], wihf0[2], Bc0, 0, 0, 0);
    Bd0 = __builtin_amdgcn_mfma_f32_16x16x32_f16(xfB[3], wihf0[3], Bd0, 0, 0, 0);
    Ba1 = __builtin_amdgcn_mfma_f32_16x16x32_f16(xfB[0], wihf1[0], Ba1, 0, 0, 0);
    Bb1 = __builtin_amdgcn_mfma_f32_16x16x32_f16(xfB[1], wihf1[1], Bb1, 0, 0, 0);
    Bc1 = __builtin_amdgcn_mfma_f32_16x16x32_f16(xfB[2], wihf1[2], Bc1, 0, 0, 0);
    Bd1 = __builtin_amdgcn_mfma_f32_16x16x32_f16(xfB[3], wihf1[3], Bd1, 0, 0, 0);

    const u64 LSBM = 0x0001000100010001ull;

    for (int t = 0; t <= tmax; ++t) {
        const int bs = t & 1;
        const u64 want = ((((t - 1) >> 1) & 1) ^ 1) ? LSBM : 0ull;
        const unsigned pub_phase = (((unsigned)t >> 1) & 1u) ^ 1u;
        const size_t pub_base = (size_t)(t & 1) * BATCH * HID;
        const size_t pol_base = (size_t)((t + 1) & 1) * BATCH * HID;

        // ================= PHASE A =================
        int id_nextA = 0;
        if (!XA) {
            const int tn = (t < tmax) ? (t + 1) : t;
            id_nextA = ids[tn * BATCH + rowbaseA + arow];
        }
        if (t > 0) {
            const u64* rowp = (const u64*)(h16 + pol_base + (rowbaseA + crow) * HID);
            unsigned* dstw = hsu + bs * HBUF_WORDS + crow * HW_STRIDE + 2 * coff;
            u64 v[4];
            unsigned pending = 0xF;
#pragma unroll
            for (int j = 0; j < 4; ++j)
                v[j] = __hip_atomic_load(rowp + coff + 32 * j,
                                         __ATOMIC_RELAXED, __HIP_MEMORY_SCOPE_AGENT);
#pragma unroll
            for (int j = 0; j < 4; ++j) {
                if (((v[j] ^ want) & LSBM) == 0) {
                    *(u64*)(dstw + 64 * j) = v[j];
                    pending &= ~(1u << j);
                }
            }
            int round = 0, guard = 0;
            while (pending) {
#pragma unroll
                for (int j = 0; j < 4; ++j) {
                    if (pending & (1u << j)) {
                        u64 x = __hip_atomic_load(rowp + coff + 32 * j,
                                                  __ATOMIC_RELAXED,
                                                  __HIP_MEMORY_SCOPE_AGENT);
                        if (((x ^ want) & LSBM) == 0) {
                            *(u64*)(dstw + 64 * j) = x;
                            pending &= ~(1u << j);
                        }
                    }
                }
                if (!pending) break;
                if (++round >= 3) __builtin_amdgcn_s_sleep(1);
                if (++guard > (1 << 20)) break;
            }
        }
        __syncthreads();

        float4v xrawA[8];
        if (!XA) {
            const float* xrow = emb + (size_t)id_nextA * DIN;
#pragma unroll
            for (int kt = 0; kt < 4; ++kt) {
                xrawA[2 * kt]     = *(const float4v*)(xrow + kt * 32 + kq * 8);
                xrawA[2 * kt + 1] = *(const float4v*)(xrow + kt * 32 + kq * 8 + 4);
            }
        }

        if (t > 0) {
            const _Float16* hb = hsh + bs * HBUF_WORDS * 2;
#pragma unroll
            for (int kt = 0; kt < 16; ++kt) {
                half8 af = *(const half8*)(hb + arow * (HW_STRIDE * 2) + kt * 32 + kq * 8);
                switch (kt & 3) {
                case 0:
                    Aa0 = __builtin_amdgcn_mfma_f32_16x16x32_f16(af, whhf0[kt], Aa0, 0, 0, 0);
                    Aa1 = __builtin_amdgcn_mfma_f32_16x16x32_f16(af, whhf1[kt], Aa1, 0, 0, 0);
                    break;
                case 1:
                    Ab0 = __builtin_amdgcn_mfma_f32_16x16x32_f16(af, whhf0[kt], Ab0, 0, 0, 0);
                    Ab1 = __builtin_amdgcn_mfma_f32_16x16x32_f16(af, whhf1[kt], Ab1, 0, 0, 0);
                    break;
                case 2:
                    Ac0 = __builtin_amdgcn_mfma_f32_16x16x32_f16(af, whhf0[kt], Ac0, 0, 0, 0);
                    Ac1 = __builtin_amdgcn_mfma_f32_16x16x32_f16(af, whhf1[kt], Ac1, 0, 0, 0);
                    break;
                default:
                    Ad0 = __builtin_amdgcn_mfma_f32_16x16x32_f16(af, whhf0[kt], Ad0, 0, 0, 0);
                    Ad1 = __builtin_amdgcn_mfma_f32_16x16x32_f16(af, whhf1[kt], Ad1, 0, 0, 0);
                }
            }
        }
        {
            const float4v g0 = (Aa0 + Ab0) + (Ac0 + Ad0);
            const float4v g1 = (Aa1 + Ab1) + (Ac1 + Ad1);
            float* gw = gs + wv * 256;
            if (lane < 32) {
                const int grow = (lane >> 4) * 4;
#pragma unroll
                for (int r = 0; r < 4; ++r) {
                    gw[(grow + r) * 32 + col]      = g0[r];
                    gw[(grow + r) * 32 + 16 + col] = g1[r];
                }
            }
            const float4v g4 = *(const float4v*)(gw + my_row * 32 + (lane & 7) * 4);
            const float i_s = sigm(g4[0]);
            const float f_s = sigm(g4[1]);
            const float g_t = tanh_fast(g4[2]);
            const float o_s = sigm(g4[3]);
            cA = f_s * cA + i_s * g_t;
            const float hn = o_s * tanh_fast(cA);
            if (t == my_tstarA)
                out[(rowbaseA + my_row) * HID + my_unit] = cA;
            unsigned short hb16 = __builtin_bit_cast(unsigned short, (_Float16)hn);
            hb16 = (unsigned short)((hb16 & 0xFFFEu) | pub_phase);
            __hip_atomic_store((unsigned short*)h16 + pub_base
                                   + (rowbaseA + my_row) * HID + my_unit,
                               hb16, __ATOMIC_RELAXED, __HIP_MEMORY_SCOPE_AGENT);
        }
        // ---- filler A: x rotate/prefetch + x-MFMA(t+1) ----
        if (XA) {
#pragma unroll
            for (int kt = 0; kt < 4; ++kt) xfA[kt] = xnA[kt];
            const int t2 = (t + 2 <= tmax) ? (t + 2) : tmax;
            const _Float16* xs2 = x_all + ((size_t)t2 * BATCH + rowbaseA + arow) * DIN;
#pragma unroll
            for (int kt = 0; kt < 4; ++kt)
                xnA[kt] = *(const half8*)(xs2 + kt * 32 + kq * 8);
        } else {
#pragma unroll
            for (int kt = 0; kt < 4; ++kt)
                xfA[kt] = cvt8(xrawA[2 * kt], xrawA[2 * kt + 1]);
        }
        Aa0 = (float4v){bias0, bias0, bias0, bias0}; Ab0 = (float4v){0,0,0,0};
        Ac0 = (float4v){0,0,0,0};                    Ad0 = (float4v){0,0,0,0};
        Aa1 = (float4v){bias1, bias1, bias1, bias1}; Ab1 = (float4v){0,0,0,0};
        Ac1 = (float4v){0,0,0,0};                    Ad1 = (float4v){0,0,0,0};
        Aa0 = __builtin_amdgcn_mfma_f32_16x16x32_f16(xfA[0], wihf0[0], Aa0, 0, 0, 0);
        Ab0 = __builtin_amdgcn_mfma_f32_16x16x32_f16(xfA[1], wihf0[1], Ab0, 0, 0, 0);
        Ac0 = __builtin_amdgcn_mfma_f32_16x16x32_f16(xfA[2], wihf0[2], Ac0, 0, 0, 0);
        Ad0 = __builtin_amdgcn_mfma_f32_16x16x32_f16(xfA[3], wihf0[3], Ad0, 0, 0, 0);
        Aa1 = __builtin_amdgcn_mfma_f32_16x16x32_f16(xfA[0], wihf1[0], Aa1, 0, 0, 0);
        Ab1 = __builtin_amdgcn_mfma_f32_16x16x32_f16(xfA[1], wihf1[1], Ab1, 0, 0, 0);
        Ac1 = __builtin_amdgcn_mfma_f32_16x16x32_f16(xfA[2], wihf1[2], Ac1, 0, 0, 0);
        Ad1 = __builtin_amdgcn_mfma_f32_16x16x32_f16(xfA[3], wihf1[3], Ad1, 0, 0, 0);

        // ================= PHASE B =================
        int id_nextB = 0;
        if (!XA) {
            const int tn = (t < tmax) ? (t + 1) : t;
            id_nextB = ids[tn * BATCH + rowbaseB + arow];
        }
        if (t > 0) {
            const u64* rowp = (const u64*)(h16 + pol_base + (rowbaseB + crow) * HID);
            unsigned* dstw = hsu + (2 + bs) * HBUF_WORDS + crow * HW_STRIDE + 2 * coff;
            u64 v[4];
            unsigned pending = 0xF;
#pragma unroll
            for (int j = 0; j < 4; ++j)
                v[j] = __hip_atomic_load(rowp + coff + 32 * j,
                                         __ATOMIC_RELAXED, __HIP_MEMORY_SCOPE_AGENT);
#pragma unroll
            for (int j = 0; j < 4; ++j) {
                if (((v[j] ^ want) & LSBM) == 0) {
                    *(u64*)(dstw + 64 * j) = v[j];
                    pending &= ~(1u << j);
                }
            }
            int round = 0, guard = 0;
            while (pending) {
#pragma unroll
                for (int j = 0; j < 4; ++j) {
                    if (pending & (1u << j)) {
                        u64 x = __hip_atomic_load(rowp + coff + 32 * j,
                                                  __ATOMIC_RELAXED,
                                                  __HIP_MEMORY_SCOPE_AGENT);
                        if (((x ^ want) & LSBM) == 0) {
                            *(u64*)(dstw + 64 * j) = x;
                            pending &= ~(1u << j);
                        }
                    }
                }
                if (!pending) break;
                if (++round >= 3) __builtin_amdgcn_s_sleep(1);
                if (++guard > (1 << 20)) break;
            }
        }
        __syncthreads();

        float4v xrawB[8];
        if (!XA) {
            const float* xrow = emb + (size_t)id_nextB * DIN;
#pragma unroll
            for (int kt = 0; kt < 4; ++kt) {
                xrawB[2 * kt]     = *(const float4v*)(xrow + kt * 32 + kq * 8);
                xrawB[2 * kt + 1] = *(const float4v*)(xrow + kt * 32 + kq * 8 + 4);
            }
        }

        if (t > 0) {
            const _Float16* hb = hsh + (2 + bs) * HBUF_WORDS * 2;
#pragma unroll
            for (int kt = 0; kt < 16; ++kt) {
                half8 af = *(const half8*)(hb + arow * (HW_STRIDE * 2) + kt * 32 + kq * 8);
                switch (kt & 3) {
                case 0:
                    Ba0 = __builtin_amdgcn_mfma_f32_16x16x32_f16(af, whhf0[kt], Ba0, 0, 0, 0);
                    Ba1 = __builtin_amdgcn_mfma_f32_16x16x32_f16(af, whhf1[kt], Ba1, 0, 0, 0);
                    break;
                case 1:
                    Bb0 = __builtin_amdgcn_mfma_f32_16x16x32_f16(af, whhf0[kt], Bb0, 0, 0, 0);
                    Bb1 = __builtin_amdgcn_mfma_f32_16x16x32_f16(af, whhf1[kt], Bb1, 0, 0, 0);
                    break;
                case 2:
                    Bc0 = __builtin_amdgcn_mfma_f32_16x16x32_f16(af, whhf0[kt], Bc0, 0, 0, 0);
                    Bc1 = __builtin_amdgcn_mfma_f32_16x16x32_f16(af, whhf1[kt], Bc1, 0, 0, 0);
                    break;
                default:
                    Bd0 = __builtin_amdgcn_mfma_f32_16x16x32_f16(af, whhf0[kt], Bd0, 0, 0, 0);
                    Bd1 = __builtin_amdgcn_mfma_f32_16x16x32_f16(af, whhf1[kt], Bd1, 0, 0, 0);
                }
            }
        }
        {
            const float4v g0 = (Ba0 + Bb0) + (Bc0 + Bd0);
            const float4v g1 = (Ba1 + Bb1) + (Bc1 + Bd1);
            float* gw = gs + wv * 256;
            if (lane < 32) {
                const int grow = (lane >> 4) * 4;
#pragma unroll
                for (int r = 0; r < 4; ++r) {
                    gw[(grow + r) * 32 + col]      = g0[r];
                    gw[(grow + r) * 32 + 16 + col] = g1[r];
                }
            }
            const float4v g4 = *(const float4v*)(gw + my_row * 32 + (lane & 7) * 4);
            const float i_s = sigm(g4[0]);
            const float f_s = sigm(g4[1]);
            const float g_t = tanh_fast(g4[2]);
            const float o_s = sigm(g4[3]);
            cB = f_s * cB + i_s * g_t;
            const float hn = o_s * tanh_fast(cB);
            if (t == my_tstarB)
                out[(rowbaseB + my_row) * HID + my_unit] = cB;
            unsigned short hb16 = __builtin_bit_cast(unsigned short, (_Float16)hn);
            hb16 = (unsigned short)((hb16 & 0xFFFEu) | pub_phase);
            __hip_atomic_store((unsigned short*)h16 + pub_base
                                   + (rowbaseB + my_row) * HID + my_unit,
                               hb16, __ATOMIC_RELAXED, __HIP_MEMORY_SCOPE_AGENT);
        }
        // ---- filler B: x rotate/prefetch + x-MFMA(t+1) ----
        if (XA) {
#pragma unroll
            for (int kt = 0; kt < 4; ++kt) xfB[kt] = xnB[kt];
            const int t2 = (t + 2 <= tmax) ? (t + 2) : tmax;
            const _Float16* xs2 = x_all + ((size_t)t2 * BATCH + rowbaseB + arow) * DIN;
#pragma unroll
            for (int kt = 0; kt < 4; ++kt)
                xnB[kt] = *(const half8*)(xs2 + kt * 32 + kq * 8);
        } else {
#pragma unroll
            for (int kt = 0; kt < 4; ++kt)
                xfB[kt] = cvt8(xrawB[2 * kt], xrawB[2 * kt + 1]);
        }
        Ba0 = (float4v){bias0, bias0, bias0, bias0}; Bb0 = (float4v){0,0,0,0};
        Bc0 = (float4v){0,0,0,0};                    Bd0 = (float4v){0,0,0,0};
        Ba1 = (float4v){bias1, bias1, bias1, bias1}; Bb1 = (float4v){0,0,0,0};
        Bc1 = (float4v){0,0,0,0};                    Bd1 = (float4v){0,0,0,0};
        Ba0 = __builtin_amdgcn_mfma_f32_16x16x32_f16(xfB[0], wihf0[0], Ba0, 0, 0, 0);
        Bb0 = __builtin_amdgcn_mfma_f32_16x16x32_f16(xfB[1], wihf0[1], Bb0, 0, 0, 0);
        Bc0 = __builtin_amdgcn_mfma_f32_16x16x32_f16(xfB[2], wihf0[2], Bc0, 0, 0, 0);
        Bd0 = __builtin_amdgcn_mfma_f32_16x16x32_f16(xfB[3], wihf0[3], Bd0, 0, 0, 0);
        Ba1 = __builtin_amdgcn_mfma_f32_16x16x32_f16(xfB[0], wihf1[0], Ba1, 0, 0, 0);
        Bb1 = __builtin_amdgcn_mfma_f32_16x16x32_f16(xfB[1], wihf1[1], Bb1, 0, 0, 0);
        Bc1 = __builtin_amdgcn_mfma_f32_16x16x32_f16(xfB[2], wihf1[2], Bc1, 0, 0, 0);
        Bd1 = __builtin_amdgcn_mfma_f32_16x16x32_f16(xfB[3], wihf1[3], Bd1, 0, 0, 0);
    }
}

extern "C" void kernel_launch(void* const* d_in, const int* in_sizes, int n_in,
                              void* d_out, int out_size, void* d_ws, size_t ws_size,
                              hipStream_t stream)
{
    const int*   ids  = (const int*)d_in[0];
    const int*   slen = (const int*)d_in[1];
    const float* emb  = (const float*)d_in[2];
    const float* wih  = (const float*)d_in[3];
    const float* whh  = (const float*)d_in[4];
    const float* bih  = (const float*)d_in[5];
    const float* bhh  = (const float*)d_in[6];
    float* out = (float*)d_out;

    _Float16* h16   = (_Float16*)((char*)d_ws + WS_H16_OFF);
    int*      bar   = (int*)((char*)d_ws + WS_BAR_OFF);
    _Float16* x_all = (_Float16*)((char*)d_ws + WS_XALL_OFF);

    if (ws_size >= WS_NEED) {
        hipMemsetAsync(bar, 0, sizeof(int), stream);
        hipLaunchKernelGGL((lstm_persistent<true>), dim3(128), dim3(256), 0, stream,
                           ids, slen, emb, wih, whh, bih, bhh, out,
                           h16, x_all, bar);
    } else {
        hipLaunchKernelGGL((lstm_persistent<false>), dim3(128), dim3(256), 0, stream,
                           ids, slen, emb, wih, whh, bih, bhh, out,
                           h16, x_all, bar);
    }
}

// Round 6
// 2612.782 us; speedup vs baseline: 1.4020x; 1.3524x over previous
//
#include <hip/hip_runtime.h>

typedef _Float16 half8 __attribute__((ext_vector_type(8)));
typedef float float4v __attribute__((ext_vector_type(4)));
typedef unsigned long long u64;

#define TSEQ  1024
#define BATCH 128
#define HID   512
#define DIN   128

// LDS: double-buffered h tile. Row stride 264 b32-words (528 halves) so the
// MFMA ds_read_b128 pattern lands 2-way max (free).
#define HW_STRIDE 264                        // b32 words per row
#define HBUF_WORDS (8 * HW_STRIDE)           // 2112 words per buffer
#define GOFF (2 * HBUF_WORDS * 4)            // 16896 B
#define LDS_BYTES (GOFF + 4 * 8 * 32 * 4)    // + per-wave gate scratch = 20992 B

// d_ws layout
#define WS_H16_OFF  0                                // [2][128][512] fp16 = 256 KiB
#define WS_BAR_OFF  (2 * BATCH * HID * 2)            // 262144
#define WS_XALL_OFF (1u << 20)                       // 1 MiB
#define WS_NEED     ((size_t)WS_XALL_OFF + (size_t)TSEQ * BATCH * DIN * 2)

__device__ inline half8 cvt8(float4v a, float4v b) {
    half8 r;
    r[0] = (_Float16)a[0]; r[1] = (_Float16)a[1];
    r[2] = (_Float16)a[2]; r[3] = (_Float16)a[3];
    r[4] = (_Float16)b[0]; r[5] = (_Float16)b[1];
    r[6] = (_Float16)b[2]; r[7] = (_Float16)b[3];
    return r;
}

// branch-free sigmoid / tanh on v_exp_f32 + v_rcp_f32
__device__ inline float sigm(float x) {
    return __builtin_amdgcn_rcpf(1.0f + __builtin_amdgcn_exp2f(-1.44269504f * x));
}
__device__ inline float tanh_fast(float x) { return 2.0f * sigm(2.0f * x) - 1.0f; }

// 16 teams x 16 CUs. Team owns rows [8t,8t+8); CU p owns units [32p,32p+32);
// wave w owns units [..+8w..). Weights VGPR-resident fp16 for the whole run.
// h handoff: RAW fp16, double-buffered, with the mantissa LSB carrying a
// phase bit ((t>>1)&1)^1 — each 2-byte value self-describes freshness, so
// relaxed AGENT atomics suffice and the exchange tile is 8 KB (untagged).
// [R1/R2/R4 lesson: every sc0/L2-local exchange variant starves or regresses
//  on gfx950 — agent scope everywhere; do not touch the exchange scope.]
// [R5 lesson: dual-team on half the grid hides latency per-step but loses
//  2x on CU count — keep 256 blocks.]
// Poison 0xAAAA has LSB 0 != first expected phase 1 -> no init required.
// Step schedule (R6 = R3 + PIPELINED POLL): at the BOTTOM of iteration t,
// after publish + x-rotate/prefetch + short sleep, ISSUE the round-0 poll
// loads for step t+1 (no wait), then run the 8 x-MFMAs / acc re-init; the
// vmcnt wait lands at the TOP of iteration t+1 at first use, so ~300-400cyc
// of the agent-load RT hides under the x-GEMM. Retry loop unchanged
// (guaranteed progress; worst case = pre-pipeline behavior).
template <bool XA>
__global__ __launch_bounds__(256, 1)
void lstm_persistent(const int* __restrict__ ids,
                     const int* __restrict__ seq_len,
                     const float* __restrict__ emb,
                     const float* __restrict__ w_ih,
                     const float* __restrict__ w_hh,
                     const float* __restrict__ b_ih,
                     const float* __restrict__ b_hh,
                     float* __restrict__ out,
                     _Float16* __restrict__ h16,      // [2][128][512] fp16
                     _Float16* __restrict__ x_all,    // [T][128][128] fp16
                     int* __restrict__ bar)
{
    __shared__ __align__(16) char smem[LDS_BYTES];
    unsigned* hsu = (unsigned*)smem;
    _Float16* hsh = (_Float16*)smem;
    float*    gs  = (float*)(smem + GOFF);

    const int tid  = threadIdx.x;
    const int lane = tid & 63;
    const int wv   = tid >> 6;
    const int team = blockIdx.x & 15;
    const int p    = blockIdx.x >> 4;
    const int rowbase   = team * 8;
    const int unit_base = p * 32 + wv * 8;

    const int col  = lane & 15;   // MFMA n / C col
    const int kq   = lane >> 4;   // MFMA k-quad
    const int arow = lane & 7;    // A row (rows 8..15 duplicate 0..7)
    const int my_row  = lane >> 3;
    const int my_unit = unit_base + (lane & 7);

    if (XA) {
        // ---- phase 0: gather x_all[t][b][:] = fp16(emb[ids[t][b]][:]) ----
        for (int pair = blockIdx.x * 256 + tid; pair < TSEQ * BATCH;
             pair += 256 * 256) {
            const float* src = emb + (size_t)ids[pair] * DIN;   // pair = t*128+b
            _Float16* dst = x_all + (size_t)pair * DIN;
#pragma unroll
            for (int k = 0; k < 16; ++k) {
                float4v a = *(const float4v*)(src + k * 8);
                float4v c = *(const float4v*)(src + k * 8 + 4);
                *(half8*)(dst + k * 8) = cvt8(a, c);
            }
        }
        // ---- one-time grid barrier (full release/acquire, only here) ----
        __threadfence();
        __syncthreads();
        if (tid == 0) {
            __hip_atomic_fetch_add(bar, 1, __ATOMIC_RELEASE,
                                   __HIP_MEMORY_SCOPE_AGENT);
            int g = 0;
            while (__hip_atomic_load(bar, __ATOMIC_ACQUIRE,
                                     __HIP_MEMORY_SCOPE_AGENT) < 256
                   && ++g < (1 << 26)) { }
        }
        __syncthreads();
        __threadfence();
    }

    int tmax = 0, my_tstar = 0;
    for (int r = 0; r < 8; ++r) {
        int s  = seq_len[rowbase + r];
        int ts = (s > 0) ? (s - 1) : 0;
        if (r == my_row) my_tstar = ts;
        tmax = (ts > tmax) ? ts : tmax;
    }

    // ---- weight fragments -> VGPRs (fp32 -> fp16), once ----
    const int wrow0 = (col & 3) * HID + unit_base + (col >> 2);
    const int wrow1 = (col & 3) * HID + unit_base + 4 + (col >> 2);
    const float bias0 = b_ih[wrow0] + b_hh[wrow0];
    const float bias1 = b_ih[wrow1] + b_hh[wrow1];

    half8 whhf0[16], whhf1[16];
#pragma unroll
    for (int kt = 0; kt < 16; ++kt) {
        const float* s0 = w_hh + (size_t)wrow0 * HID + kt * 32 + kq * 8;
        const float* s1 = w_hh + (size_t)wrow1 * HID + kt * 32 + kq * 8;
        whhf0[kt] = cvt8(*(const float4v*)s0, *(const float4v*)(s0 + 4));
        whhf1[kt] = cvt8(*(const float4v*)s1, *(const float4v*)(s1 + 4));
    }
    half8 wihf0[4], wihf1[4];
#pragma unroll
    for (int kt = 0; kt < 4; ++kt) {
        const float* s0 = w_ih + (size_t)wrow0 * DIN + kt * 32 + kq * 8;
        const float* s1 = w_ih + (size_t)wrow1 * DIN + kt * 32 + kq * 8;
        wihf0[kt] = cvt8(*(const float4v*)s0, *(const float4v*)(s0 + 4));
        wihf1[kt] = cvt8(*(const float4v*)s1, *(const float4v*)(s1 + 4));
    }

    float c_state = 0.0f;
    const int crow = tid >> 5;    // poll/staging: row 0..7, 32 threads/row
    const int coff = tid & 31;    // thread polls u64s {coff + 32j}, j=0..3

    // ---- x fragment pipeline ----
    half8 xf[4], xn[4];
    if (XA) {
        const _Float16* x0 = x_all + ((size_t)0 * BATCH + rowbase + arow) * DIN;
        const int t1 = (tmax > 0) ? 1 : 0;
        const _Float16* x1 = x_all + ((size_t)t1 * BATCH + rowbase + arow) * DIN;
#pragma unroll
        for (int kt = 0; kt < 4; ++kt) {
            xf[kt] = *(const half8*)(x0 + kt * 32 + kq * 8);
            xn[kt] = *(const half8*)(x1 + kt * 32 + kq * 8);
        }
    } else {
        const int id0 = ids[rowbase + arow];
        const float* xrow = emb + (size_t)id0 * DIN;
#pragma unroll
        for (int kt = 0; kt < 4; ++kt) {
            const float* s = xrow + kt * 32 + kq * 8;
            xf[kt] = cvt8(*(const float4v*)s, *(const float4v*)(s + 4));
        }
    }

    // ---- acc(0) = bias + x(0) @ Wih, spread over 8 chains (a..d x 2) ----
    float4v a0 = {bias0, bias0, bias0, bias0}, b0 = {0,0,0,0}, c0 = {0,0,0,0}, d0 = {0,0,0,0};
    float4v a1 = {bias1, bias1, bias1, bias1}, b1 = {0,0,0,0}, c1 = {0,0,0,0}, d1 = {0,0,0,0};
    a0 = __builtin_amdgcn_mfma_f32_16x16x32_f16(xf[0], wihf0[0], a0, 0, 0, 0);
    b0 = __builtin_amdgcn_mfma_f32_16x16x32_f16(xf[1], wihf0[1], b0, 0, 0, 0);
    c0 = __builtin_amdgcn_mfma_f32_16x16x32_f16(xf[2], wihf0[2], c0, 0, 0, 0);
    d0 = __builtin_amdgcn_mfma_f32_16x16x32_f16(xf[3], wihf0[3], d0, 0, 0, 0);
    a1 = __builtin_amdgcn_mfma_f32_16x16x32_f16(xf[0], wihf1[0], a1, 0, 0, 0);
    b1 = __builtin_amdgcn_mfma_f32_16x16x32_f16(xf[1], wihf1[1], b1, 0, 0, 0);
    c1 = __builtin_amdgcn_mfma_f32_16x16x32_f16(xf[2], wihf1[2], c1, 0, 0, 0);
    d1 = __builtin_amdgcn_mfma_f32_16x16x32_f16(xf[3], wihf1[3], d1, 0, 0, 0);

    const u64 LSBM = 0x0001000100010001ull;

    u64 pv[4];   // pre-issued round-0 poll values (valid at top when t>0)

    for (int t = 0; t <= tmax; ++t) {
        const int bs = t & 1;    // LDS h-tile buffer for this step
        int id_next = 0;
        if (!XA) {
            const int tn = (t < tmax) ? (t + 1) : t;
            id_next = ids[tn * BATCH + rowbase + arow];
        }

        if (t > 0) {
            // ---- poll check: round-0 values were ISSUED last iteration; the
            //      vmcnt wait lands here (after the x-MFMA block) ----
            const u64* rowp = (const u64*)(h16
                + (size_t)((t + 1) & 1) * BATCH * HID + (rowbase + crow) * HID);
            const u64 want = ((((t - 1) >> 1) & 1) ^ 1) ? LSBM : 0ull;
            unsigned* dstw = hsu + bs * HBUF_WORDS + crow * HW_STRIDE + 2 * coff;
            unsigned pending = 0xF;
#pragma unroll
            for (int j = 0; j < 4; ++j) {
                if (((pv[j] ^ want) & LSBM) == 0) {
                    *(u64*)(dstw + 64 * j) = pv[j];
                    pending &= ~(1u << j);
                }
            }
            int round = 0, guard = 0;
            while (pending) {
#pragma unroll
                for (int j = 0; j < 4; ++j) {
                    if (pending & (1u << j)) {
                        u64 x = __hip_atomic_load(rowp + coff + 32 * j,
                                                  __ATOMIC_RELAXED,
                                                  __HIP_MEMORY_SCOPE_AGENT);
                        if (((x ^ want) & LSBM) == 0) {
                            *(u64*)(dstw + 64 * j) = x;
                            pending &= ~(1u << j);
                        }
                    }
                }
                if (!pending) break;
                if (++round >= 3) __builtin_amdgcn_s_sleep(1);
                if (++guard > (1 << 20)) break;   // anti-hang safety valve
            }
        }
        __syncthreads();   // the ONLY barrier per step (h-tile double-buffered)

        float4v xraw[8];
        if (!XA) {
            // fallback: issue emb(t+1) raw loads here (h-MFMA shadow)
            const float* xrow = emb + (size_t)id_next * DIN;
#pragma unroll
            for (int kt = 0; kt < 4; ++kt) {
                xraw[2 * kt]     = *(const float4v*)(xrow + kt * 32 + kq * 8);
                xraw[2 * kt + 1] = *(const float4v*)(xrow + kt * 32 + kq * 8 + 4);
            }
        }

        if (t > 0) {
            // ---- h MFMAs: 16 kt over 8 chains (dependent depth 4) ----
            const _Float16* hb = hsh + bs * HBUF_WORDS * 2;
#pragma unroll
            for (int kt = 0; kt < 16; ++kt) {
                half8 af = *(const half8*)(hb + arow * (HW_STRIDE * 2) + kt * 32 + kq * 8);
                switch (kt & 3) {
                case 0:
                    a0 = __builtin_amdgcn_mfma_f32_16x16x32_f16(af, whhf0[kt], a0, 0, 0, 0);
                    a1 = __builtin_amdgcn_mfma_f32_16x16x32_f16(af, whhf1[kt], a1, 0, 0, 0);
                    break;
                case 1:
                    b0 = __builtin_amdgcn_mfma_f32_16x16x32_f16(af, whhf0[kt], b0, 0, 0, 0);
                    b1 = __builtin_amdgcn_mfma_f32_16x16x32_f16(af, whhf1[kt], b1, 0, 0, 0);
                    break;
                case 2:
                    c0 = __builtin_amdgcn_mfma_f32_16x16x32_f16(af, whhf0[kt], c0, 0, 0, 0);
                    c1 = __builtin_amdgcn_mfma_f32_16x16x32_f16(af, whhf1[kt], c1, 0, 0, 0);
                    break;
                default:
                    d0 = __builtin_amdgcn_mfma_f32_16x16x32_f16(af, whhf0[kt], d0, 0, 0, 0);
                    d1 = __builtin_amdgcn_mfma_f32_16x16x32_f16(af, whhf1[kt], d1, 0, 0, 0);
                }
            }
        }
        const float4v g0 = (a0 + b0) + (c0 + d0);
        const float4v g1 = (a1 + b1) + (c1 + d1);

        // ---- regroup i,f,g,o per (row,unit) via per-wave LDS scratch ----
        float* gw = gs + wv * 256;
        if (lane < 32) {
            const int grow = (lane >> 4) * 4;
#pragma unroll
            for (int r = 0; r < 4; ++r) {
                gw[(grow + r) * 32 + col]      = g0[r];
                gw[(grow + r) * 32 + 16 + col] = g1[r];
            }
        }
        const float4v g4 = *(const float4v*)(gw + my_row * 32 + (lane & 7) * 4);

        const float i_s = sigm(g4[0]);
        const float f_s = sigm(g4[1]);
        const float g_t = tanh_fast(g4[2]);
        const float o_s = sigm(g4[3]);
        c_state = f_s * c_state + i_s * g_t;
        const float hn = o_s * tanh_fast(c_state);

        if (t == my_tstar)
            out[(rowbase + my_row) * HID + my_unit] = c_state;

        // ---- publish h: raw fp16, mantissa LSB = phase; fire-and-forget ----
        {
            const unsigned pub_phase = (((unsigned)t >> 1) & 1u) ^ 1u;
            unsigned short hb16 = __builtin_bit_cast(unsigned short, (_Float16)hn);
            hb16 = (unsigned short)((hb16 & 0xFFFEu) | pub_phase);
            __hip_atomic_store((unsigned short*)h16
                                   + (size_t)(t & 1) * BATCH * HID
                                   + (rowbase + my_row) * HID + my_unit,
                               hb16, __ATOMIC_RELAXED, __HIP_MEMORY_SCOPE_AGENT);
        }

        // ---- filler part 1: x rotate + prefetch (XA) / fp16 convert (!XA) ----
        if (XA) {
#pragma unroll
            for (int kt = 0; kt < 4; ++kt) xf[kt] = xn[kt];
            const int t2 = (t + 2 <= tmax) ? (t + 2) : tmax;
            const _Float16* xs2 = x_all + ((size_t)t2 * BATCH + rowbase + arow) * DIN;
#pragma unroll
            for (int kt = 0; kt < 4; ++kt)
                xn[kt] = *(const half8*)(xs2 + kt * 32 + kq * 8);
        } else {
#pragma unroll
            for (int kt = 0; kt < 4; ++kt)
                xf[kt] = cvt8(xraw[2 * kt], xraw[2 * kt + 1]);
        }

        // ---- EARLY-ISSUE the round-0 poll loads for step t+1 ----
        // Peers publish h(t) into buffer t&1 (phase ((t>>1)&1)^1); the short
        // sleep pushes the sample past store->IF visibility, and the x-MFMA
        // block below runs inside the load round trip (wait is at next top).
        if (t < tmax) {
            __builtin_amdgcn_s_sleep(4);
            const u64* rowp_n = (const u64*)(h16
                + (size_t)(t & 1) * BATCH * HID + (rowbase + crow) * HID);
#pragma unroll
            for (int j = 0; j < 4; ++j)
                pv[j] = __hip_atomic_load(rowp_n + coff + 32 * j,
                                          __ATOMIC_RELAXED,
                                          __HIP_MEMORY_SCOPE_AGENT);
        }

        // ---- filler part 2: acc re-init + x-MFMA(t+1) (poll RT shadow) ----
        a0 = (float4v){bias0, bias0, bias0, bias0}; b0 = (float4v){0,0,0,0};
        c0 = (float4v){0,0,0,0};                    d0 = (float4v){0,0,0,0};
        a1 = (float4v){bias1, bias1, bias1, bias1}; b1 = (float4v){0,0,0,0};
        c1 = (float4v){0,0,0,0};                    d1 = (float4v){0,0,0,0};
        a0 = __builtin_amdgcn_mfma_f32_16x16x32_f16(xf[0], wihf0[0], a0, 0, 0, 0);
        b0 = __builtin_amdgcn_mfma_f32_16x16x32_f16(xf[1], wihf0[1], b0, 0, 0, 0);
        c0 = __builtin_amdgcn_mfma_f32_16x16x32_f16(xf[2], wihf0[2], c0, 0, 0, 0);
        d0 = __builtin_amdgcn_mfma_f32_16x16x32_f16(xf[3], wihf0[3], d0, 0, 0, 0);
        a1 = __builtin_amdgcn_mfma_f32_16x16x32_f16(xf[0], wihf1[0], a1, 0, 0, 0);
        b1 = __builtin_amdgcn_mfma_f32_16x16x32_f16(xf[1], wihf1[1], b1, 0, 0, 0);
        c1 = __builtin_amdgcn_mfma_f32_16x16x32_f16(xf[2], wihf1[2], c1, 0, 0, 0);
        d1 = __builtin_amdgcn_mfma_f32_16x16x32_f16(xf[3], wihf1[3], d1, 0, 0, 0);
    }
}

extern "C" void kernel_launch(void* const* d_in, const int* in_sizes, int n_in,
                              void* d_out, int out_size, void* d_ws, size_t ws_size,
                              hipStream_t stream)
{
    const int*   ids  = (const int*)d_in[0];
    const int*   slen = (const int*)d_in[1];
    const float* emb  = (const float*)d_in[2];
    const float* wih  = (const float*)d_in[3];
    const float* whh  = (const float*)d_in[4];
    const float* bih  = (const float*)d_in[5];
    const float* bhh  = (const float*)d_in[6];
    float* out = (float*)d_out;

    _Float16* h16   = (_Float16*)((char*)d_ws + WS_H16_OFF);
    int*      bar   = (int*)((char*)d_ws + WS_BAR_OFF);
    _Float16* x_all = (_Float16*)((char*)d_ws + WS_XALL_OFF);

    if (ws_size >= WS_NEED) {
        hipMemsetAsync(bar, 0, sizeof(int), stream);
        hipLaunchKernelGGL((lstm_persistent<true>), dim3(256), dim3(256), 0, stream,
                           ids, slen, emb, wih, whh, bih, bhh, out,
                           h16, x_all, bar);
    } else {
        hipLaunchKernelGGL((lstm_persistent<false>), dim3(256), dim3(256), 0, stream,
                           ids, slen, emb, wih, whh, bih, bhh, out,
                           h16, x_all, bar);
    }
}

// Round 7
// 2015.918 us; speedup vs baseline: 1.8172x; 1.2961x over previous
//
#include <hip/hip_runtime.h>

typedef _Float16 half8 __attribute__((ext_vector_type(8)));
typedef float float4v __attribute__((ext_vector_type(4)));
typedef unsigned long long u64;

#define TSEQ  1024
#define BATCH 128
#define HID   512
#define DIN   128

// LDS: double-buffered h tile. Row stride 264 b32-words (528 halves) so the
// MFMA ds_read_b128 pattern lands 2-way max (free).
#define HW_STRIDE 264                        // b32 words per row
#define HBUF_WORDS (8 * HW_STRIDE)           // 2112 words per buffer
#define GOFF (2 * HBUF_WORDS * 4)            // 16896 B
#define LDS_BYTES (GOFF + 4 * 8 * 32 * 4)    // + per-wave gate scratch = 20992 B

// d_ws layout
#define WS_H16_OFF  0                                // [2][128][512] fp16 = 256 KiB
#define WS_BAR_OFF  (2 * BATCH * HID * 2)            // 262144
#define WS_XALL_OFF (1u << 20)                       // 1 MiB
#define WS_NEED     ((size_t)WS_XALL_OFF + (size_t)TSEQ * BATCH * DIN * 2)

__device__ inline half8 cvt8(float4v a, float4v b) {
    half8 r;
    r[0] = (_Float16)a[0]; r[1] = (_Float16)a[1];
    r[2] = (_Float16)a[2]; r[3] = (_Float16)a[3];
    r[4] = (_Float16)b[0]; r[5] = (_Float16)b[1];
    r[6] = (_Float16)b[2]; r[7] = (_Float16)b[3];
    return r;
}

// branch-free sigmoid / tanh on v_exp_f32 + v_rcp_f32
__device__ inline float sigm(float x) {
    return __builtin_amdgcn_rcpf(1.0f + __builtin_amdgcn_exp2f(-1.44269504f * x));
}
__device__ inline float tanh_fast(float x) { return 2.0f * sigm(2.0f * x) - 1.0f; }

// 16 teams x 16 CUs. Team owns rows [8t,8t+8); CU p owns units [32p,32p+32);
// wave w owns units [..+8w..). Weights VGPR-resident fp16 for the whole run.
// h handoff: RAW fp16, double-buffered, with the mantissa LSB carrying a
// phase bit ((t>>1)&1)^1 — each 2-byte value self-describes freshness, so
// relaxed AGENT atomics suffice and the exchange tile is 8 KB (untagged).
// Team members share an XCD under the %8 round-robin dispatch, so the
// exchange is L2-served (FETCH evidence: ~5% of poll volume hits EA).
// [R1/R2/R4: never change the exchange scope. R5: keep 256 blocks.
//  R6: never early-issue poll loads — value is sampled at service time.]
// R7 changes vs R3:
//  (a) COALESCED PUBLISH: per-wave LDS staging (128B of the gate scratch)
//      -> 16 lanes/wave store u64s: 64x8B per block instead of 256x2B.
//      4x fewer device-scope store transactions -> faster drain/visibility.
//  (b) ADAPTIVE pre-poll sleep: per-wave slp in [1,24] x64cyc, +1 on
//      round-0 miss, -1 on hit — converges to the actual visibility delay.
// Poison 0xAAAA has LSB 0 != first expected phase 1 -> no init required.
// Step: poll(h(t-1)) -> barrier -> h-MFMAs -> gates -> publish(coalesced)
// -> filler (x rotate/prefetch + x-MFMA(t+1)) -> adaptive sleep -> loop.
template <bool XA>
__global__ __launch_bounds__(256, 1)
void lstm_persistent(const int* __restrict__ ids,
                     const int* __restrict__ seq_len,
                     const float* __restrict__ emb,
                     const float* __restrict__ w_ih,
                     const float* __restrict__ w_hh,
                     const float* __restrict__ b_ih,
                     const float* __restrict__ b_hh,
                     float* __restrict__ out,
                     _Float16* __restrict__ h16,      // [2][128][512] fp16
                     _Float16* __restrict__ x_all,    // [T][128][128] fp16
                     int* __restrict__ bar)
{
    __shared__ __align__(16) char smem[LDS_BYTES];
    unsigned* hsu = (unsigned*)smem;
    _Float16* hsh = (_Float16*)smem;
    float*    gs  = (float*)(smem + GOFF);

    const int tid  = threadIdx.x;
    const int lane = tid & 63;
    const int wv   = tid >> 6;
    const int team = blockIdx.x & 15;
    const int p    = blockIdx.x >> 4;
    const int rowbase   = team * 8;
    const int unit_base = p * 32 + wv * 8;

    const int col  = lane & 15;   // MFMA n / C col
    const int kq   = lane >> 4;   // MFMA k-quad
    const int arow = lane & 7;    // A row (rows 8..15 duplicate 0..7)
    const int my_row  = lane >> 3;
    const int my_unit = unit_base + (lane & 7);

    if (XA) {
        // ---- phase 0: gather x_all[t][b][:] = fp16(emb[ids[t][b]][:]) ----
        for (int pair = blockIdx.x * 256 + tid; pair < TSEQ * BATCH;
             pair += 256 * 256) {
            const float* src = emb + (size_t)ids[pair] * DIN;   // pair = t*128+b
            _Float16* dst = x_all + (size_t)pair * DIN;
#pragma unroll
            for (int k = 0; k < 16; ++k) {
                float4v a = *(const float4v*)(src + k * 8);
                float4v c = *(const float4v*)(src + k * 8 + 4);
                *(half8*)(dst + k * 8) = cvt8(a, c);
            }
        }
        // ---- one-time grid barrier (full release/acquire, only here) ----
        __threadfence();
        __syncthreads();
        if (tid == 0) {
            __hip_atomic_fetch_add(bar, 1, __ATOMIC_RELEASE,
                                   __HIP_MEMORY_SCOPE_AGENT);
            int g = 0;
            while (__hip_atomic_load(bar, __ATOMIC_ACQUIRE,
                                     __HIP_MEMORY_SCOPE_AGENT) < 256
                   && ++g < (1 << 26)) { }
        }
        __syncthreads();
        __threadfence();
    }

    int tmax = 0, my_tstar = 0;
    for (int r = 0; r < 8; ++r) {
        int s  = seq_len[rowbase + r];
        int ts = (s > 0) ? (s - 1) : 0;
        if (r == my_row) my_tstar = ts;
        tmax = (ts > tmax) ? ts : tmax;
    }

    // ---- weight fragments -> VGPRs (fp32 -> fp16), once ----
    const int wrow0 = (col & 3) * HID + unit_base + (col >> 2);
    const int wrow1 = (col & 3) * HID + unit_base + 4 + (col >> 2);
    const float bias0 = b_ih[wrow0] + b_hh[wrow0];
    const float bias1 = b_ih[wrow1] + b_hh[wrow1];

    half8 whhf0[16], whhf1[16];
#pragma unroll
    for (int kt = 0; kt < 16; ++kt) {
        const float* s0 = w_hh + (size_t)wrow0 * HID + kt * 32 + kq * 8;
        const float* s1 = w_hh + (size_t)wrow1 * HID + kt * 32 + kq * 8;
        whhf0[kt] = cvt8(*(const float4v*)s0, *(const float4v*)(s0 + 4));
        whhf1[kt] = cvt8(*(const float4v*)s1, *(const float4v*)(s1 + 4));
    }
    half8 wihf0[4], wihf1[4];
#pragma unroll
    for (int kt = 0; kt < 4; ++kt) {
        const float* s0 = w_ih + (size_t)wrow0 * DIN + kt * 32 + kq * 8;
        const float* s1 = w_ih + (size_t)wrow1 * DIN + kt * 32 + kq * 8;
        wihf0[kt] = cvt8(*(const float4v*)s0, *(const float4v*)(s0 + 4));
        wihf1[kt] = cvt8(*(const float4v*)s1, *(const float4v*)(s1 + 4));
    }

    float c_state = 0.0f;
    const int crow = tid >> 5;    // poll/staging: row 0..7, 32 threads/row
    const int coff = tid & 31;    // thread polls u64s {coff + 32j}, j=0..3

    // ---- x fragment pipeline ----
    half8 xf[4], xn[4];
    if (XA) {
        const _Float16* x0 = x_all + ((size_t)0 * BATCH + rowbase + arow) * DIN;
        const int t1 = (tmax > 0) ? 1 : 0;
        const _Float16* x1 = x_all + ((size_t)t1 * BATCH + rowbase + arow) * DIN;
#pragma unroll
        for (int kt = 0; kt < 4; ++kt) {
            xf[kt] = *(const half8*)(x0 + kt * 32 + kq * 8);
            xn[kt] = *(const half8*)(x1 + kt * 32 + kq * 8);
        }
    } else {
        const int id0 = ids[rowbase + arow];
        const float* xrow = emb + (size_t)id0 * DIN;
#pragma unroll
        for (int kt = 0; kt < 4; ++kt) {
            const float* s = xrow + kt * 32 + kq * 8;
            xf[kt] = cvt8(*(const float4v*)s, *(const float4v*)(s + 4));
        }
    }

    // ---- acc(0) = bias + x(0) @ Wih, spread over 8 chains (a..d x 2) ----
    float4v a0 = {bias0, bias0, bias0, bias0}, b0 = {0,0,0,0}, c0 = {0,0,0,0}, d0 = {0,0,0,0};
    float4v a1 = {bias1, bias1, bias1, bias1}, b1 = {0,0,0,0}, c1 = {0,0,0,0}, d1 = {0,0,0,0};
    a0 = __builtin_amdgcn_mfma_f32_16x16x32_f16(xf[0], wihf0[0], a0, 0, 0, 0);
    b0 = __builtin_amdgcn_mfma_f32_16x16x32_f16(xf[1], wihf0[1], b0, 0, 0, 0);
    c0 = __builtin_amdgcn_mfma_f32_16x16x32_f16(xf[2], wihf0[2], c0, 0, 0, 0);
    d0 = __builtin_amdgcn_mfma_f32_16x16x32_f16(xf[3], wihf0[3], d0, 0, 0, 0);
    a1 = __builtin_amdgcn_mfma_f32_16x16x32_f16(xf[0], wihf1[0], a1, 0, 0, 0);
    b1 = __builtin_amdgcn_mfma_f32_16x16x32_f16(xf[1], wihf1[1], b1, 0, 0, 0);
    c1 = __builtin_amdgcn_mfma_f32_16x16x32_f16(xf[2], wihf1[2], c1, 0, 0, 0);
    d1 = __builtin_amdgcn_mfma_f32_16x16x32_f16(xf[3], wihf1[3], d1, 0, 0, 0);

    const u64 LSBM = 0x0001000100010001ull;

    int slp = 6;   // per-wave adaptive pre-poll delay, units of 64 cyc

    for (int t = 0; t <= tmax; ++t) {
        const int bs = t & 1;    // LDS h-tile buffer for this step
        int id_next = 0;
        if (!XA) {
            const int tn = (t < tmax) ? (t + 1) : t;
            id_next = ids[tn * BATCH + rowbase + arow];
        }

        if (t > 0) {
            // ---- poll teammates' phase-tagged fp16 h (poll IS the load) ----
            const u64* rowp = (const u64*)(h16
                + (size_t)((t + 1) & 1) * BATCH * HID + (rowbase + crow) * HID);
            const u64 want = ((((t - 1) >> 1) & 1) ^ 1) ? LSBM : 0ull;
            unsigned* dstw = hsu + bs * HBUF_WORDS + crow * HW_STRIDE + 2 * coff;
            u64 v[4];
            unsigned pending = 0xF;
#pragma unroll
            for (int j = 0; j < 4; ++j)
                v[j] = __hip_atomic_load(rowp + coff + 32 * j,
                                         __ATOMIC_RELAXED, __HIP_MEMORY_SCOPE_AGENT);
#pragma unroll
            for (int j = 0; j < 4; ++j) {
                if (((v[j] ^ want) & LSBM) == 0) {
                    *(u64*)(dstw + 64 * j) = v[j];
                    pending &= ~(1u << j);
                }
            }
            const bool miss0 = (pending != 0);
            int round = 0, guard = 0;
            while (pending) {
#pragma unroll
                for (int j = 0; j < 4; ++j) {
                    if (pending & (1u << j)) {
                        u64 x = __hip_atomic_load(rowp + coff + 32 * j,
                                                  __ATOMIC_RELAXED,
                                                  __HIP_MEMORY_SCOPE_AGENT);
                        if (((x ^ want) & LSBM) == 0) {
                            *(u64*)(dstw + 64 * j) = x;
                            pending &= ~(1u << j);
                        }
                    }
                }
                if (!pending) break;
                if (++round >= 3) __builtin_amdgcn_s_sleep(1);
                if (++guard > (1 << 20)) break;   // anti-hang safety valve
            }
            // ---- adapt the pre-poll delay (wave-uniform feedback) ----
            if (__any((int)miss0)) slp = (slp < 24) ? slp + 1 : 24;
            else                   slp = (slp > 1)  ? slp - 1 : 1;
        }
        __syncthreads();   // the ONLY barrier per step (h-tile double-buffered)

        float4v xraw[8];
        if (!XA) {
            // fallback: issue emb(t+1) raw loads here (h-MFMA shadow)
            const float* xrow = emb + (size_t)id_next * DIN;
#pragma unroll
            for (int kt = 0; kt < 4; ++kt) {
                xraw[2 * kt]     = *(const float4v*)(xrow + kt * 32 + kq * 8);
                xraw[2 * kt + 1] = *(const float4v*)(xrow + kt * 32 + kq * 8 + 4);
            }
        }

        if (t > 0) {
            // ---- h MFMAs: 16 kt over 8 chains (dependent depth 4) ----
            const _Float16* hb = hsh + bs * HBUF_WORDS * 2;
#pragma unroll
            for (int kt = 0; kt < 16; ++kt) {
                half8 af = *(const half8*)(hb + arow * (HW_STRIDE * 2) + kt * 32 + kq * 8);
                switch (kt & 3) {
                case 0:
                    a0 = __builtin_amdgcn_mfma_f32_16x16x32_f16(af, whhf0[kt], a0, 0, 0, 0);
                    a1 = __builtin_amdgcn_mfma_f32_16x16x32_f16(af, whhf1[kt], a1, 0, 0, 0);
                    break;
                case 1:
                    b0 = __builtin_amdgcn_mfma_f32_16x16x32_f16(af, whhf0[kt], b0, 0, 0, 0);
                    b1 = __builtin_amdgcn_mfma_f32_16x16x32_f16(af, whhf1[kt], b1, 0, 0, 0);
                    break;
                case 2:
                    c0 = __builtin_amdgcn_mfma_f32_16x16x32_f16(af, whhf0[kt], c0, 0, 0, 0);
                    c1 = __builtin_amdgcn_mfma_f32_16x16x32_f16(af, whhf1[kt], c1, 0, 0, 0);
                    break;
                default:
                    d0 = __builtin_amdgcn_mfma_f32_16x16x32_f16(af, whhf0[kt], d0, 0, 0, 0);
                    d1 = __builtin_amdgcn_mfma_f32_16x16x32_f16(af, whhf1[kt], d1, 0, 0, 0);
                }
            }
        }
        const float4v g0 = (a0 + b0) + (c0 + d0);
        const float4v g1 = (a1 + b1) + (c1 + d1);

        // ---- regroup i,f,g,o per (row,unit) via per-wave LDS scratch ----
        float* gw = gs + wv * 256;
        if (lane < 32) {
            const int grow = (lane >> 4) * 4;
#pragma unroll
            for (int r = 0; r < 4; ++r) {
                gw[(grow + r) * 32 + col]      = g0[r];
                gw[(grow + r) * 32 + 16 + col] = g1[r];
            }
        }
        const float4v g4 = *(const float4v*)(gw + my_row * 32 + (lane & 7) * 4);

        const float i_s = sigm(g4[0]);
        const float f_s = sigm(g4[1]);
        const float g_t = tanh_fast(g4[2]);
        const float o_s = sigm(g4[3]);
        c_state = f_s * c_state + i_s * g_t;
        const float hn = o_s * tanh_fast(c_state);

        if (t == my_tstar)
            out[(rowbase + my_row) * HID + my_unit] = c_state;

        // ---- COALESCED publish: stage tagged fp16 in per-wave LDS (128B of
        //      the gate scratch, intra-wave lgkm order), then 16 lanes/wave
        //      store u64s -> 64x8B per block instead of 256x2B ----
        {
            const unsigned pub_phase = (((unsigned)t >> 1) & 1u) ^ 1u;
            unsigned short hb16 = __builtin_bit_cast(unsigned short, (_Float16)hn);
            hb16 = (unsigned short)((hb16 & 0xFFFEu) | pub_phase);
            unsigned short* ps = (unsigned short*)gw;      // 128B staging
            ps[my_row * 8 + (lane & 7)] = hb16;
            if (lane < 16) {
                const int r = lane >> 1, j = lane & 1;
                const u64 pk = *(const u64*)(ps + r * 8 + j * 4);
                __hip_atomic_store((u64*)((unsigned short*)h16
                                       + (size_t)(t & 1) * BATCH * HID
                                       + (rowbase + r) * HID + unit_base + j * 4),
                                   pk, __ATOMIC_RELAXED, __HIP_MEMORY_SCOPE_AGENT);
            }
        }

        // ---- filler between publish and next poll: x pipeline + x-MFMA(t+1)
        //      then the ADAPTIVE sleep (converged to visibility delay) ----
        if (XA) {
#pragma unroll
            for (int kt = 0; kt < 4; ++kt) xf[kt] = xn[kt];
            const int t2 = (t + 2 <= tmax) ? (t + 2) : tmax;
            const _Float16* xs2 = x_all + ((size_t)t2 * BATCH + rowbase + arow) * DIN;
#pragma unroll
            for (int kt = 0; kt < 4; ++kt)
                xn[kt] = *(const half8*)(xs2 + kt * 32 + kq * 8);
        } else {
#pragma unroll
            for (int kt = 0; kt < 4; ++kt)
                xf[kt] = cvt8(xraw[2 * kt], xraw[2 * kt + 1]);
        }

        a0 = (float4v){bias0, bias0, bias0, bias0}; b0 = (float4v){0,0,0,0};
        c0 = (float4v){0,0,0,0};                    d0 = (float4v){0,0,0,0};
        a1 = (float4v){bias1, bias1, bias1, bias1}; b1 = (float4v){0,0,0,0};
        c1 = (float4v){0,0,0,0};                    d1 = (float4v){0,0,0,0};
        a0 = __builtin_amdgcn_mfma_f32_16x16x32_f16(xf[0], wihf0[0], a0, 0, 0, 0);
        b0 = __builtin_amdgcn_mfma_f32_16x16x32_f16(xf[1], wihf0[1], b0, 0, 0, 0);
        c0 = __builtin_amdgcn_mfma_f32_16x16x32_f16(xf[2], wihf0[2], c0, 0, 0, 0);
        d0 = __builtin_amdgcn_mfma_f32_16x16x32_f16(xf[3], wihf0[3], d0, 0, 0, 0);
        a1 = __builtin_amdgcn_mfma_f32_16x16x32_f16(xf[0], wihf1[0], a1, 0, 0, 0);
        b1 = __builtin_amdgcn_mfma_f32_16x16x32_f16(xf[1], wihf1[1], b1, 0, 0, 0);
        c1 = __builtin_amdgcn_mfma_f32_16x16x32_f16(xf[2], wihf1[2], c1, 0, 0, 0);
        d1 = __builtin_amdgcn_mfma_f32_16x16x32_f16(xf[3], wihf1[3], d1, 0, 0, 0);

        // adaptive pre-poll delay (s_sleep takes an immediate -> loop of 1s)
        if (t < tmax)
            for (int i = 0; i < slp; ++i) __builtin_amdgcn_s_sleep(1);
    }
}

extern "C" void kernel_launch(void* const* d_in, const int* in_sizes, int n_in,
                              void* d_out, int out_size, void* d_ws, size_t ws_size,
                              hipStream_t stream)
{
    const int*   ids  = (const int*)d_in[0];
    const int*   slen = (const int*)d_in[1];
    const float* emb  = (const float*)d_in[2];
    const float* wih  = (const float*)d_in[3];
    const float* whh  = (const float*)d_in[4];
    const float* bih  = (const float*)d_in[5];
    const float* bhh  = (const float*)d_in[6];
    float* out = (float*)d_out;

    _Float16* h16   = (_Float16*)((char*)d_ws + WS_H16_OFF);
    int*      bar   = (int*)((char*)d_ws + WS_BAR_OFF);
    _Float16* x_all = (_Float16*)((char*)d_ws + WS_XALL_OFF);

    if (ws_size >= WS_NEED) {
        hipMemsetAsync(bar, 0, sizeof(int), stream);
        hipLaunchKernelGGL((lstm_persistent<true>), dim3(256), dim3(256), 0, stream,
                           ids, slen, emb, wih, whh, bih, bhh, out,
                           h16, x_all, bar);
    } else {
        hipLaunchKernelGGL((lstm_persistent<false>), dim3(256), dim3(256), 0, stream,
                           ids, slen, emb, wih, whh, bih, bhh, out,
                           h16, x_all, bar);
    }
}